// Round 2
// baseline (641.263 us; speedup 1.0000x reference)
//
#include <hip/hip_runtime.h>
#include <math.h>

#define NROWS 16384
#define GATES 5
#define HDIM 512

using bf16x8 = __attribute__((ext_vector_type(8))) short;
using f32x4  = __attribute__((ext_vector_type(4))) float;

__device__ inline float b2f(unsigned short s) {
  unsigned int u = ((unsigned int)s) << 16;
  return __builtin_bit_cast(float, u);
}
__device__ inline unsigned short f2b(float f) {
  unsigned int u = __builtin_bit_cast(unsigned int, f);
  u += 0x7fffu + ((u >> 16) & 1u);   // RNE
  return (unsigned short)(u >> 16);
}

__device__ inline void gload_lds16(const unsigned short* g, unsigned short* l) {
  __builtin_amdgcn_global_load_lds(
      (const __attribute__((address_space(1))) unsigned int*)(g),
      (__attribute__((address_space(3))) unsigned int*)(l), 16, 0, 0);
}

// ---------------- packing / conversion kernels (f32 -> bf16) ----------------

__global__ void pack_x(const float* __restrict__ word,
                       const float* __restrict__ tag,
                       const float* __restrict__ rel,
                       unsigned short* __restrict__ xcat) {
  int idx = blockIdx.x * 256 + threadIdx.x;       // N*512
  int n = idx >> 9, c = idx & 511;
  float v = 0.f;
  if (c < 300)      v = word[n * 300 + c];
  else if (c < 350) v = tag[n * 50 + (c - 300)];
  else if (c < 400) v = rel[n * 50 + (c - 350)];
  xcat[idx] = f2b(v);
}

__global__ void pack_w(const float* __restrict__ Ww,
                       const float* __restrict__ Wt,
                       const float* __restrict__ Wr,
                       unsigned short* __restrict__ Wcat) {
  int idx = blockIdx.x * 256 + threadIdx.x;       // G*512*512
  int gh = idx >> 9;                              // g*512 + h
  int c = idx & 511;
  float v = 0.f;
  if (c < 300)      v = Ww[gh * 300 + c];
  else if (c < 350) v = Wt[gh * 50 + (c - 300)];
  else if (c < 400) v = Wr[gh * 50 + (c - 350)];
  Wcat[idx] = f2b(v);
}

__global__ void cvt_bf16(const float* __restrict__ in,
                         unsigned short* __restrict__ out, int n) {
  int i = (blockIdx.x * 256 + threadIdx.x) * 4;
  if (i >= n) return;
  float4 v = *(const float4*)(in + i);
  ushort4 o;
  o.x = f2b(v.x); o.y = f2b(v.y); o.z = f2b(v.z); o.w = f2b(v.w);
  *(ushort4*)(out + i) = o;
}

__global__ void pack_bias(const float* __restrict__ bw, const float* __restrict__ bt,
                          const float* __restrict__ br, const float* __restrict__ bh,
                          const float* __restrict__ bl, const float* __restrict__ bhp,
                          const float* __restrict__ bk,
                          float* bias0, float* bias1, float* bias2, float* biasD) {
  int i = blockIdx.x * 256 + threadIdx.x;         // G*512
  if (i < GATES * HDIM) {
    bias0[i] = bw[i] + bt[i] + br[i];
    bias1[i] = bh[i];
    bias2[i] = bl[i];
    biasD[i] = bhp[i] + bk[i];
  }
}

// ---------------- GEMM (m97 structure: 128x128 tile, BK=64, 4 waves) ----------------
// MODE 0: Out = tanh(A[g?]*W[g]^T + bias[g])           (A per-gate if aPerGate)
// MODE 1: Out = act_g(A1*W1[g]^T + A2*W2[g]^T + bias[g] + Madd[g])  K=1024 split

template<int MODE>
__global__ __launch_bounds__(256) void gemm_nt(
    const unsigned short* __restrict__ A1, const unsigned short* __restrict__ A2,
    const unsigned short* __restrict__ W1, const unsigned short* __restrict__ W2,
    const float* __restrict__ bias,
    const unsigned short* __restrict__ Madd,
    unsigned short* __restrict__ Out,
    int aPerGate, int Ksteps)
{
  __shared__ __align__(16) unsigned short Alds[128 * 64];
  __shared__ __align__(16) unsigned short Blds[128 * 64];

  const int t = threadIdx.x;
  const int row0 = blockIdx.x * 128;   // N tiles
  const int col0 = blockIdx.y * 128;   // H tiles
  const int g = blockIdx.z;

  const size_t wslab = (size_t)g * HDIM * HDIM;
  const size_t aslab = aPerGate ? (size_t)g * NROWS * HDIM : 0;

  f32x4 acc[4][4];
#pragma unroll
  for (int mi = 0; mi < 4; ++mi)
#pragma unroll
    for (int ni = 0; ni < 4; ++ni)
      acc[mi][ni] = (f32x4){0.f, 0.f, 0.f, 0.f};

  const int w = t >> 6, l = t & 63;
  const int wrow = (w >> 1) * 64, wcol = (w & 1) * 64;
  const int fr = l & 15, kb = l >> 4;
  const int sr = t >> 3;            // staging row 0..31
  const int sc = (t & 7) * 8;       // staging col (elements)

  for (int s = 0; s < Ksteps; ++s) {
    const int k0 = s * 64;
    const unsigned short* Abase;
    const unsigned short* Wbase;
    int kloc;
    if (MODE == 1 && k0 >= 512) {
      Abase = A2; Wbase = W2 + wslab; kloc = k0 - 512;
    } else {
      Abase = A1 + aslab; Wbase = W1 + wslab; kloc = k0;
    }
#pragma unroll
    for (int i = 0; i < 4; ++i) {
      const unsigned short* ga = Abase + (size_t)(row0 + i * 32 + sr) * HDIM + kloc + sc;
      gload_lds16(ga, &Alds[(i * 32 + sr) * 64 + sc]);
    }
#pragma unroll
    for (int i = 0; i < 4; ++i) {
      const unsigned short* gb = Wbase + (size_t)(col0 + i * 32 + sr) * HDIM + kloc + sc;
      gload_lds16(gb, &Blds[(i * 32 + sr) * 64 + sc]);
    }
    __syncthreads();

#pragma unroll
    for (int kk = 0; kk < 64; kk += 32) {
      bf16x8 af[4], bfr[4];
#pragma unroll
      for (int mi = 0; mi < 4; ++mi)
        af[mi] = *reinterpret_cast<const bf16x8*>(&Alds[(wrow + mi * 16 + fr) * 64 + kk + kb * 8]);
#pragma unroll
      for (int ni = 0; ni < 4; ++ni)
        bfr[ni] = *reinterpret_cast<const bf16x8*>(&Blds[(wcol + ni * 16 + fr) * 64 + kk + kb * 8]);
#pragma unroll
      for (int mi = 0; mi < 4; ++mi)
#pragma unroll
        for (int ni = 0; ni < 4; ++ni)
          acc[mi][ni] = __builtin_amdgcn_mfma_f32_16x16x32_bf16(af[mi], bfr[ni], acc[mi][ni], 0, 0, 0);
    }
    __syncthreads();
  }

  // epilogue: C/D layout col=lane&15, row=(lane>>4)*4+j   [m89/m91]
  const int crow = (l >> 4) * 4, ccol = l & 15;
  unsigned short* outg = Out + (size_t)g * NROWS * HDIM;
#pragma unroll
  for (int mi = 0; mi < 4; ++mi) {
#pragma unroll
    for (int ni = 0; ni < 4; ++ni) {
      const int hcol = col0 + wcol + ni * 16 + ccol;
      const float bb = bias[g * HDIM + hcol];
#pragma unroll
      for (int j = 0; j < 4; ++j) {
        const int nrow = row0 + wrow + mi * 16 + crow + j;
        float v = acc[mi][ni][j] + bb;
        if (MODE == 1) {
          v += b2f(Madd[(size_t)g * NROWS * HDIM + (size_t)nrow * HDIM + hcol]);
          v = (g < 4) ? (1.f / (1.f + expf(-v))) : tanhf(v);
        } else {
          v = tanhf(v);
        }
        outg[(size_t)nrow * HDIM + hcol] = f2b(v);
      }
    }
  }
}

// ---------------- final elementwise combine (f32 q/c_prev, f32 out) ----------------

__device__ inline float exb(const uint4& v, int j) {
  unsigned int wd = ((const unsigned int*)&v)[j >> 1];
  return b2f((unsigned short)(wd >> ((j & 1) * 16)));
}

__global__ void combine(const unsigned short* __restrict__ gates,
                        const float* __restrict__ q,
                        const float* __restrict__ cp,
                        float* __restrict__ out) {
  const size_t NM = (size_t)NROWS * HDIM;
  size_t i8 = ((size_t)blockIdx.x * 256 + threadIdx.x) * 8;
  if (i8 >= NM) return;
  uint4 gi = *(const uint4*)(gates + 0 * NM + i8);
  uint4 gf = *(const uint4*)(gates + 1 * NM + i8);
  uint4 gl = *(const uint4*)(gates + 2 * NM + i8);
  uint4 go = *(const uint4*)(gates + 3 * NM + i8);
  uint4 gu = *(const uint4*)(gates + 4 * NM + i8);
  float4 q0 = *(const float4*)(q + i8);
  float4 q1 = *(const float4*)(q + i8 + 4);
  float4 p0 = *(const float4*)(cp + i8);
  float4 p1 = *(const float4*)(cp + i8 + 4);
  float qv[8] = {q0.x, q0.y, q0.z, q0.w, q1.x, q1.y, q1.z, q1.w};
  float pv[8] = {p0.x, p0.y, p0.z, p0.w, p1.x, p1.y, p1.z, p1.w};
  float hv[8], cv[8];
#pragma unroll
  for (int j = 0; j < 8; ++j) {
    float c = exb(gi, j) * exb(gu, j) + exb(gf, j) * qv[j] + exb(gl, j) * pv[j];
    hv[j] = exb(go, j) * tanhf(c);
    cv[j] = c;
  }
  *(float4*)(out + i8)      = make_float4(hv[0], hv[1], hv[2], hv[3]);
  *(float4*)(out + i8 + 4)  = make_float4(hv[4], hv[5], hv[6], hv[7]);
  *(float4*)(out + NM + i8)     = make_float4(cv[0], cv[1], cv[2], cv[3]);
  *(float4*)(out + NM + i8 + 4) = make_float4(cv[4], cv[5], cv[6], cv[7]);
}

// ---------------- launch ----------------

extern "C" void kernel_launch(void* const* d_in, const int* in_sizes, int n_in,
                              void* d_out, int out_size, void* d_ws, size_t ws_size,
                              hipStream_t stream) {
  const float* word  = (const float*)d_in[0];
  const float* tag   = (const float*)d_in[1];
  const float* rel   = (const float*)d_in[2];
  const float* kin   = (const float*)d_in[3];
  const float* qin   = (const float*)d_in[4];
  const float* hprev = (const float*)d_in[5];
  const float* cprev = (const float*)d_in[6];
  const float* Ww    = (const float*)d_in[7];
  const float* bw    = (const float*)d_in[8];
  const float* Wt    = (const float*)d_in[9];
  const float* bt    = (const float*)d_in[10];
  const float* Wr    = (const float*)d_in[11];
  const float* br    = (const float*)d_in[12];
  const float* Wh    = (const float*)d_in[13];
  const float* bh    = (const float*)d_in[14];
  const float* Wl    = (const float*)d_in[15];
  const float* bl    = (const float*)d_in[16];
  const float* Whp   = (const float*)d_in[17];
  const float* bhp   = (const float*)d_in[18];
  const float* Wk    = (const float*)d_in[19];
  const float* bk    = (const float*)d_in[20];

  char* ws = (char*)d_ws;
  unsigned short* xcat   = (unsigned short*)(ws);                 // 16,777,216 B
  unsigned short* Wcat   = (unsigned short*)(ws + 16777216);      //  2,621,440 B
  unsigned short* Whb    = (unsigned short*)(ws + 19398656);      //  2,621,440 B
  unsigned short* Wlb    = (unsigned short*)(ws + 22020096);      //  2,621,440 B
  unsigned short* Whpb   = (unsigned short*)(ws + 24641536);      //  2,621,440 B
  unsigned short* Wkb    = (unsigned short*)(ws + 27262976);      //  2,621,440 B
  unsigned short* hprevb = (unsigned short*)(ws + 29884416);      // 16,777,216 B
  unsigned short* kb16   = (unsigned short*)(ws + 46661632);      // 16,777,216 B
  float* bias0           = (float*)(ws + 63438848);               //     10,240 B
  float* bias1           = (float*)(ws + 63449088);
  float* bias2           = (float*)(ws + 63459328);
  float* biasD           = (float*)(ws + 63469568);
  unsigned short* bufA   = (unsigned short*)(ws + 63479808);      // 83,886,080 B
  unsigned short* bufB   = (unsigned short*)(ws + 147365888);     // 83,886,080 B
  // total: 231,251,968 B

  pack_x<<<32768, 256, 0, stream>>>(word, tag, rel, xcat);
  pack_w<<<5120, 256, 0, stream>>>(Ww, Wt, Wr, Wcat);
  cvt_bf16<<<1280, 256, 0, stream>>>(Wh, Whb, 1310720);
  cvt_bf16<<<1280, 256, 0, stream>>>(Wl, Wlb, 1310720);
  cvt_bf16<<<1280, 256, 0, stream>>>(Whp, Whpb, 1310720);
  cvt_bf16<<<1280, 256, 0, stream>>>(Wk, Wkb, 1310720);
  cvt_bf16<<<8192, 256, 0, stream>>>(hprev, hprevb, 8388608);
  cvt_bf16<<<8192, 256, 0, stream>>>(kin, kb16, 8388608);
  pack_bias<<<10, 256, 0, stream>>>(bw, bt, br, bh, bl, bhp, bk, bias0, bias1, bias2, biasD);

  dim3 grid(NROWS / 128, HDIM / 128, GATES);
  // h0 = tanh(xcat W0^T + b0)
  gemm_nt<0><<<grid, 256, 0, stream>>>(xcat, nullptr, Wcat, nullptr, bias0, nullptr, bufA, 0, 8);
  // h1 = tanh(h0 Whid^T + bhid)
  gemm_nt<0><<<grid, 256, 0, stream>>>(bufA, nullptr, Whb, nullptr, bias1, nullptr, bufB, 1, 8);
  // m = tanh(h1 Wlast^T + blast)
  gemm_nt<0><<<grid, 256, 0, stream>>>(bufB, nullptr, Wlb, nullptr, bias2, nullptr, bufA, 1, 8);
  // gates = act(hprev Whp^T + k Wk^T + bhp + bk + m)
  gemm_nt<1><<<grid, 256, 0, stream>>>(hprevb, kb16, Whpb, Wkb, biasD, bufA, bufB, 0, 16);
  // c = i*u + f_down*q + f_left*c_prev ; h = o*tanh(c)
  combine<<<4096, 256, 0, stream>>>(bufB, qin, cprev, (float*)d_out);
}

// Round 3
// 560.271 us; speedup vs baseline: 1.1446x; 1.1446x over previous
//
#include <hip/hip_runtime.h>
#include <math.h>

#define NROWS 16384
#define GATES 5
#define HDIM 512

using bf16x8 = __attribute__((ext_vector_type(8))) short;
using f32x4  = __attribute__((ext_vector_type(4))) float;

__device__ inline float b2f(unsigned short s) {
  unsigned int u = ((unsigned int)s) << 16;
  return __builtin_bit_cast(float, u);
}
__device__ inline unsigned short f2b(float f) {
  unsigned int u = __builtin_bit_cast(unsigned int, f);
  u += 0x7fffu + ((u >> 16) & 1u);   // RNE
  return (unsigned short)(u >> 16);
}

// fast activations: v_exp_f32 (2^x) + v_rcp_f32, ~5 inst, saturate correctly
__device__ inline float fast_sigmoid(float x) {
  float t = __builtin_amdgcn_exp2f(-1.4426950408889634f * x);
  return __builtin_amdgcn_rcpf(1.0f + t);
}
__device__ inline float fast_tanh(float x) {
  float t = __builtin_amdgcn_exp2f(2.8853900817779268f * x);
  return 1.0f - 2.0f * __builtin_amdgcn_rcpf(1.0f + t);
}

__device__ inline void gload_lds16(const unsigned short* g, unsigned short* l) {
  __builtin_amdgcn_global_load_lds(
      (const __attribute__((address_space(1))) unsigned int*)(g),
      (__attribute__((address_space(3))) unsigned int*)(l), 16, 0, 0);
}

// ---------------- packing / conversion kernels (f32 -> bf16) ----------------

__global__ void pack_x(const float* __restrict__ word,
                       const float* __restrict__ tag,
                       const float* __restrict__ rel,
                       unsigned short* __restrict__ xcat) {
  int idx = blockIdx.x * 256 + threadIdx.x;       // N*512
  int n = idx >> 9, c = idx & 511;
  float v = 0.f;
  if (c < 300)      v = word[n * 300 + c];
  else if (c < 350) v = tag[n * 50 + (c - 300)];
  else if (c < 400) v = rel[n * 50 + (c - 350)];
  xcat[idx] = f2b(v);
}

__global__ void pack_w(const float* __restrict__ Ww,
                       const float* __restrict__ Wt,
                       const float* __restrict__ Wr,
                       unsigned short* __restrict__ Wcat) {
  int idx = blockIdx.x * 256 + threadIdx.x;       // G*512*512
  int gh = idx >> 9;                              // g*512 + h
  int c = idx & 511;
  float v = 0.f;
  if (c < 300)      v = Ww[gh * 300 + c];
  else if (c < 350) v = Wt[gh * 50 + (c - 300)];
  else if (c < 400) v = Wr[gh * 50 + (c - 350)];
  Wcat[idx] = f2b(v);
}

__global__ void cvt_bf16(const float* __restrict__ in,
                         unsigned short* __restrict__ out, int n) {
  int i = (blockIdx.x * 256 + threadIdx.x) * 4;
  if (i >= n) return;
  float4 v = *(const float4*)(in + i);
  ushort4 o;
  o.x = f2b(v.x); o.y = f2b(v.y); o.z = f2b(v.z); o.w = f2b(v.w);
  *(ushort4*)(out + i) = o;
}

__global__ void pack_bias(const float* __restrict__ bw, const float* __restrict__ bt,
                          const float* __restrict__ br, const float* __restrict__ bh,
                          const float* __restrict__ bl, const float* __restrict__ bhp,
                          const float* __restrict__ bk,
                          float* bias0, float* bias1, float* bias2, float* biasD) {
  int i = blockIdx.x * 256 + threadIdx.x;         // G*512
  if (i < GATES * HDIM) {
    bias0[i] = bw[i] + bt[i] + br[i];
    bias1[i] = bh[i];
    bias2[i] = bl[i];
    biasD[i] = bhp[i] + bk[i];
  }
}

// ---------------- GEMM (m97 structure: 128x128 tile, BK=64, 4 waves) ----------------
// MODE 0: Out = tanh(A[g?]*W[g]^T + bias[g])           (A per-gate if aPerGate)
// MODE 1: Out = act_g(A1*W1[g]^T + A2*W2[g]^T + bias[g] + Madd[g])  K=1024 split

template<int MODE>
__global__ __launch_bounds__(256) void gemm_nt(
    const unsigned short* __restrict__ A1, const unsigned short* __restrict__ A2,
    const unsigned short* __restrict__ W1, const unsigned short* __restrict__ W2,
    const float* __restrict__ bias,
    const unsigned short* __restrict__ Madd,
    unsigned short* __restrict__ Out,
    int aPerGate, int Ksteps)
{
  __shared__ __align__(16) unsigned short Alds[128 * 64];
  __shared__ __align__(16) unsigned short Blds[128 * 64];

  const int t = threadIdx.x;
  const int row0 = blockIdx.x * 128;   // N tiles
  const int col0 = blockIdx.y * 128;   // H tiles
  const int g = blockIdx.z;

  const size_t wslab = (size_t)g * HDIM * HDIM;
  const size_t aslab = aPerGate ? (size_t)g * NROWS * HDIM : 0;

  f32x4 acc[4][4];
#pragma unroll
  for (int mi = 0; mi < 4; ++mi)
#pragma unroll
    for (int ni = 0; ni < 4; ++ni)
      acc[mi][ni] = (f32x4){0.f, 0.f, 0.f, 0.f};

  const int w = t >> 6, l = t & 63;
  const int wrow = (w >> 1) * 64, wcol = (w & 1) * 64;
  const int fr = l & 15, kb = l >> 4;
  const int sr = t >> 3;            // staging row 0..31
  const int sc = (t & 7) * 8;       // staging col (elements)

  for (int s = 0; s < Ksteps; ++s) {
    const int k0 = s * 64;
    const unsigned short* Abase;
    const unsigned short* Wbase;
    int kloc;
    if (MODE == 1 && k0 >= 512) {
      Abase = A2; Wbase = W2 + wslab; kloc = k0 - 512;
    } else {
      Abase = A1 + aslab; Wbase = W1 + wslab; kloc = k0;
    }
#pragma unroll
    for (int i = 0; i < 4; ++i) {
      const unsigned short* ga = Abase + (size_t)(row0 + i * 32 + sr) * HDIM + kloc + sc;
      gload_lds16(ga, &Alds[(i * 32 + sr) * 64 + sc]);
    }
#pragma unroll
    for (int i = 0; i < 4; ++i) {
      const unsigned short* gb = Wbase + (size_t)(col0 + i * 32 + sr) * HDIM + kloc + sc;
      gload_lds16(gb, &Blds[(i * 32 + sr) * 64 + sc]);
    }
    __syncthreads();

#pragma unroll
    for (int kk = 0; kk < 64; kk += 32) {
      bf16x8 af[4], bfr[4];
#pragma unroll
      for (int mi = 0; mi < 4; ++mi)
        af[mi] = *reinterpret_cast<const bf16x8*>(&Alds[(wrow + mi * 16 + fr) * 64 + kk + kb * 8]);
#pragma unroll
      for (int ni = 0; ni < 4; ++ni)
        bfr[ni] = *reinterpret_cast<const bf16x8*>(&Blds[(wcol + ni * 16 + fr) * 64 + kk + kb * 8]);
#pragma unroll
      for (int mi = 0; mi < 4; ++mi)
#pragma unroll
        for (int ni = 0; ni < 4; ++ni)
          acc[mi][ni] = __builtin_amdgcn_mfma_f32_16x16x32_bf16(af[mi], bfr[ni], acc[mi][ni], 0, 0, 0);
    }
    __syncthreads();
  }

  // epilogue: C/D layout col=lane&15, row=(lane>>4)*4+j   [m89/m91]
  const int crow = (l >> 4) * 4, ccol = l & 15;
  unsigned short* outg = Out + (size_t)g * NROWS * HDIM;
#pragma unroll
  for (int mi = 0; mi < 4; ++mi) {
#pragma unroll
    for (int ni = 0; ni < 4; ++ni) {
      const int hcol = col0 + wcol + ni * 16 + ccol;
      const float bb = bias[g * HDIM + hcol];
#pragma unroll
      for (int j = 0; j < 4; ++j) {
        const int nrow = row0 + wrow + mi * 16 + crow + j;
        float v = acc[mi][ni][j] + bb;
        if (MODE == 1) {
          v += b2f(Madd[(size_t)g * NROWS * HDIM + (size_t)nrow * HDIM + hcol]);
          v = (g < 4) ? fast_sigmoid(v) : fast_tanh(v);
        } else {
          v = fast_tanh(v);
        }
        outg[(size_t)nrow * HDIM + hcol] = f2b(v);
      }
    }
  }
}

// ---------------- final elementwise combine (f32 q/c_prev, f32 out) ----------------

__device__ inline float exb(const uint4& v, int j) {
  unsigned int wd = ((const unsigned int*)&v)[j >> 1];
  return b2f((unsigned short)(wd >> ((j & 1) * 16)));
}

__global__ void combine(const unsigned short* __restrict__ gates,
                        const float* __restrict__ q,
                        const float* __restrict__ cp,
                        float* __restrict__ out) {
  const size_t NM = (size_t)NROWS * HDIM;
  size_t i8 = ((size_t)blockIdx.x * 256 + threadIdx.x) * 8;
  if (i8 >= NM) return;
  uint4 gi = *(const uint4*)(gates + 0 * NM + i8);
  uint4 gf = *(const uint4*)(gates + 1 * NM + i8);
  uint4 gl = *(const uint4*)(gates + 2 * NM + i8);
  uint4 go = *(const uint4*)(gates + 3 * NM + i8);
  uint4 gu = *(const uint4*)(gates + 4 * NM + i8);
  float4 q0 = *(const float4*)(q + i8);
  float4 q1 = *(const float4*)(q + i8 + 4);
  float4 p0 = *(const float4*)(cp + i8);
  float4 p1 = *(const float4*)(cp + i8 + 4);
  float qv[8] = {q0.x, q0.y, q0.z, q0.w, q1.x, q1.y, q1.z, q1.w};
  float pv[8] = {p0.x, p0.y, p0.z, p0.w, p1.x, p1.y, p1.z, p1.w};
  float hv[8], cv[8];
#pragma unroll
  for (int j = 0; j < 8; ++j) {
    float c = exb(gi, j) * exb(gu, j) + exb(gf, j) * qv[j] + exb(gl, j) * pv[j];
    hv[j] = exb(go, j) * fast_tanh(c);
    cv[j] = c;
  }
  *(float4*)(out + i8)      = make_float4(hv[0], hv[1], hv[2], hv[3]);
  *(float4*)(out + i8 + 4)  = make_float4(hv[4], hv[5], hv[6], hv[7]);
  *(float4*)(out + NM + i8)     = make_float4(cv[0], cv[1], cv[2], cv[3]);
  *(float4*)(out + NM + i8 + 4) = make_float4(cv[4], cv[5], cv[6], cv[7]);
}

// ---------------- launch ----------------

extern "C" void kernel_launch(void* const* d_in, const int* in_sizes, int n_in,
                              void* d_out, int out_size, void* d_ws, size_t ws_size,
                              hipStream_t stream) {
  const float* word  = (const float*)d_in[0];
  const float* tag   = (const float*)d_in[1];
  const float* rel   = (const float*)d_in[2];
  const float* kin   = (const float*)d_in[3];
  const float* qin   = (const float*)d_in[4];
  const float* hprev = (const float*)d_in[5];
  const float* cprev = (const float*)d_in[6];
  const float* Ww    = (const float*)d_in[7];
  const float* bw    = (const float*)d_in[8];
  const float* Wt    = (const float*)d_in[9];
  const float* bt    = (const float*)d_in[10];
  const float* Wr    = (const float*)d_in[11];
  const float* br    = (const float*)d_in[12];
  const float* Wh    = (const float*)d_in[13];
  const float* bh    = (const float*)d_in[14];
  const float* Wl    = (const float*)d_in[15];
  const float* bl    = (const float*)d_in[16];
  const float* Whp   = (const float*)d_in[17];
  const float* bhp   = (const float*)d_in[18];
  const float* Wk    = (const float*)d_in[19];
  const float* bk    = (const float*)d_in[20];

  char* ws = (char*)d_ws;
  unsigned short* xcat   = (unsigned short*)(ws);                 // 16,777,216 B
  unsigned short* Wcat   = (unsigned short*)(ws + 16777216);      //  2,621,440 B
  unsigned short* Whb    = (unsigned short*)(ws + 19398656);      //  2,621,440 B
  unsigned short* Wlb    = (unsigned short*)(ws + 22020096);      //  2,621,440 B
  unsigned short* Whpb   = (unsigned short*)(ws + 24641536);      //  2,621,440 B
  unsigned short* Wkb    = (unsigned short*)(ws + 27262976);      //  2,621,440 B
  unsigned short* hprevb = (unsigned short*)(ws + 29884416);      // 16,777,216 B
  unsigned short* kb16   = (unsigned short*)(ws + 46661632);      // 16,777,216 B
  float* bias0           = (float*)(ws + 63438848);               //     10,240 B
  float* bias1           = (float*)(ws + 63449088);
  float* bias2           = (float*)(ws + 63459328);
  float* biasD           = (float*)(ws + 63469568);
  unsigned short* bufA   = (unsigned short*)(ws + 63479808);      // 83,886,080 B
  unsigned short* bufB   = (unsigned short*)(ws + 147365888);     // 83,886,080 B
  // total: 231,251,968 B

  pack_x<<<32768, 256, 0, stream>>>(word, tag, rel, xcat);
  pack_w<<<5120, 256, 0, stream>>>(Ww, Wt, Wr, Wcat);
  cvt_bf16<<<1280, 256, 0, stream>>>(Wh, Whb, 1310720);
  cvt_bf16<<<1280, 256, 0, stream>>>(Wl, Wlb, 1310720);
  cvt_bf16<<<1280, 256, 0, stream>>>(Whp, Whpb, 1310720);
  cvt_bf16<<<1280, 256, 0, stream>>>(Wk, Wkb, 1310720);
  cvt_bf16<<<8192, 256, 0, stream>>>(hprev, hprevb, 8388608);
  cvt_bf16<<<8192, 256, 0, stream>>>(kin, kb16, 8388608);
  pack_bias<<<10, 256, 0, stream>>>(bw, bt, br, bh, bl, bhp, bk, bias0, bias1, bias2, biasD);

  dim3 grid(NROWS / 128, HDIM / 128, GATES);
  // h0 = tanh(xcat W0^T + b0)
  gemm_nt<0><<<grid, 256, 0, stream>>>(xcat, nullptr, Wcat, nullptr, bias0, nullptr, bufA, 0, 8);
  // h1 = tanh(h0 Whid^T + bhid)
  gemm_nt<0><<<grid, 256, 0, stream>>>(bufA, nullptr, Whb, nullptr, bias1, nullptr, bufB, 1, 8);
  // m = tanh(h1 Wlast^T + blast)
  gemm_nt<0><<<grid, 256, 0, stream>>>(bufB, nullptr, Wlb, nullptr, bias2, nullptr, bufA, 1, 8);
  // gates = act(hprev Whp^T + k Wk^T + bhp + bk + m)
  gemm_nt<1><<<grid, 256, 0, stream>>>(hprevb, kb16, Whpb, Wkb, biasD, bufA, bufB, 0, 16);
  // c = i*u + f_down*q + f_left*c_prev ; h = o*tanh(c)
  combine<<<4096, 256, 0, stream>>>(bufB, qin, cprev, (float*)d_out);
}

// Round 4
// 537.723 us; speedup vs baseline: 1.1926x; 1.0419x over previous
//
#include <hip/hip_runtime.h>
#include <math.h>

#define NROWS 16384
#define GATES 5
#define HDIM 512

using bf16x8 = __attribute__((ext_vector_type(8))) short;
using f32x4  = __attribute__((ext_vector_type(4))) float;

__device__ inline float b2f(unsigned short s) {
  unsigned int u = ((unsigned int)s) << 16;
  return __builtin_bit_cast(float, u);
}
__device__ inline unsigned short f2b(float f) {
  unsigned int u = __builtin_bit_cast(unsigned int, f);
  u += 0x7fffu + ((u >> 16) & 1u);   // RNE
  return (unsigned short)(u >> 16);
}

// fast activations: v_exp_f32 (2^x) + v_rcp_f32, ~5 inst, saturate correctly
__device__ inline float fast_sigmoid(float x) {
  float t = __builtin_amdgcn_exp2f(-1.4426950408889634f * x);
  return __builtin_amdgcn_rcpf(1.0f + t);
}
__device__ inline float fast_tanh(float x) {
  float t = __builtin_amdgcn_exp2f(2.8853900817779268f * x);
  return 1.0f - 2.0f * __builtin_amdgcn_rcpf(1.0f + t);
}

__device__ inline void gload_lds16(const unsigned short* g, unsigned short* l) {
  __builtin_amdgcn_global_load_lds(
      (const __attribute__((address_space(1))) unsigned int*)(g),
      (__attribute__((address_space(3))) unsigned int*)(l), 16, 0, 0);
}

// ---------------- packing / conversion kernels (f32 -> bf16) ----------------

__global__ void pack_x(const float* __restrict__ word,
                       const float* __restrict__ tag,
                       const float* __restrict__ rel,
                       unsigned short* __restrict__ xcat) {
  int idx = blockIdx.x * 256 + threadIdx.x;       // N*512
  int n = idx >> 9, c = idx & 511;
  float v = 0.f;
  if (c < 300)      v = word[n * 300 + c];
  else if (c < 350) v = tag[n * 50 + (c - 300)];
  else if (c < 400) v = rel[n * 50 + (c - 350)];
  xcat[idx] = f2b(v);
}

__global__ void pack_w(const float* __restrict__ Ww,
                       const float* __restrict__ Wt,
                       const float* __restrict__ Wr,
                       unsigned short* __restrict__ Wcat) {
  int idx = blockIdx.x * 256 + threadIdx.x;       // G*512*512
  int gh = idx >> 9;                              // g*512 + h
  int c = idx & 511;
  float v = 0.f;
  if (c < 300)      v = Ww[gh * 300 + c];
  else if (c < 350) v = Wt[gh * 50 + (c - 300)];
  else if (c < 400) v = Wr[gh * 50 + (c - 350)];
  Wcat[idx] = f2b(v);
}

__global__ void cvt_bf16(const float* __restrict__ in,
                         unsigned short* __restrict__ out, int n) {
  int i = (blockIdx.x * 256 + threadIdx.x) * 4;
  if (i >= n) return;
  float4 v = *(const float4*)(in + i);
  ushort4 o;
  o.x = f2b(v.x); o.y = f2b(v.y); o.z = f2b(v.z); o.w = f2b(v.w);
  *(ushort4*)(out + i) = o;
}

__global__ void pack_bias(const float* __restrict__ bw, const float* __restrict__ bt,
                          const float* __restrict__ br, const float* __restrict__ bh,
                          const float* __restrict__ bl, const float* __restrict__ bhp,
                          const float* __restrict__ bk,
                          float* bias0, float* bias1, float* bias2, float* biasD) {
  int i = blockIdx.x * 256 + threadIdx.x;         // G*512
  if (i < GATES * HDIM) {
    bias0[i] = bw[i] + bt[i] + br[i];
    bias1[i] = bh[i];
    bias2[i] = bl[i];
    biasD[i] = bhp[i] + bk[i];
  }
}

// ---------------- GEMM: 128x128 tile, BK=64, 4 waves, 2-phase dbuf prefetch ----
// grid: x = col_tile*GATES + gate (20), y = row_tile (128)  -> A-tile L2 reuse
// MODE 0: Out = tanh(A[g?]*W[g]^T + bias[g])
// MODE 1: Out = act_g(A1*W1[g]^T + A2*W2[g]^T + bias[g] + Madd[g])  K=1024 split

template<int MODE>
__global__ __launch_bounds__(256) void gemm_nt(
    const unsigned short* __restrict__ A1, const unsigned short* __restrict__ A2,
    const unsigned short* __restrict__ W1, const unsigned short* __restrict__ W2,
    const float* __restrict__ bias,
    const unsigned short* __restrict__ Madd,
    unsigned short* __restrict__ Out,
    int aPerGate, int Ksteps)
{
  __shared__ __align__(16) unsigned short Alds[2][128 * 64];
  __shared__ __align__(16) unsigned short Blds[2][128 * 64];

  const int t = threadIdx.x;
  const int g    = blockIdx.x % GATES;
  const int col0 = (blockIdx.x / GATES) * 128;   // H tiles
  const int row0 = blockIdx.y * 128;             // N tiles

  const size_t wslab = (size_t)g * HDIM * HDIM;
  const size_t aslab = aPerGate ? (size_t)g * NROWS * HDIM : 0;

  f32x4 acc[4][4];
#pragma unroll
  for (int mi = 0; mi < 4; ++mi)
#pragma unroll
    for (int ni = 0; ni < 4; ++ni)
      acc[mi][ni] = (f32x4){0.f, 0.f, 0.f, 0.f};

  const int w = t >> 6, l = t & 63;
  const int wrow = (w >> 1) * 64, wcol = (w & 1) * 64;
  const int fr = l & 15, kb = l >> 4;
  const int sr = t >> 3;            // staging row 0..31
  const int sc = (t & 7) * 8;       // staging col (elements)

  auto stage = [&](int s, int buf) {
    const int k0 = s * 64;
    const unsigned short* Abase;
    const unsigned short* Wbase;
    int kloc;
    if (MODE == 1 && k0 >= 512) {
      Abase = A2; Wbase = W2 + wslab; kloc = k0 - 512;
    } else {
      Abase = A1 + aslab; Wbase = W1 + wslab; kloc = k0;
    }
#pragma unroll
    for (int i = 0; i < 4; ++i) {
      gload_lds16(Abase + (size_t)(row0 + i * 32 + sr) * HDIM + kloc + sc,
                  &Alds[buf][(i * 32 + sr) * 64 + sc]);
      gload_lds16(Wbase + (size_t)(col0 + i * 32 + sr) * HDIM + kloc + sc,
                  &Blds[buf][(i * 32 + sr) * 64 + sc]);
    }
  };

  // prologue: stage tile 0, drain, barrier
  stage(0, 0);
  __syncthreads();

  int cur = 0;
  for (int s = 0; s < Ksteps; ++s) {
    // issue next tile's loads first — they fly during this tile's compute
    if (s + 1 < Ksteps) stage(s + 1, cur ^ 1);

#pragma unroll
    for (int kk = 0; kk < 64; kk += 32) {
      bf16x8 af[4], bfr[4];
#pragma unroll
      for (int mi = 0; mi < 4; ++mi)
        af[mi] = *reinterpret_cast<const bf16x8*>(&Alds[cur][(wrow + mi * 16 + fr) * 64 + kk + kb * 8]);
#pragma unroll
      for (int ni = 0; ni < 4; ++ni)
        bfr[ni] = *reinterpret_cast<const bf16x8*>(&Blds[cur][(wcol + ni * 16 + fr) * 64 + kk + kb * 8]);
#pragma unroll
      for (int mi = 0; mi < 4; ++mi)
#pragma unroll
        for (int ni = 0; ni < 4; ++ni)
          acc[mi][ni] = __builtin_amdgcn_mfma_f32_16x16x32_bf16(af[mi], bfr[ni], acc[mi][ni], 0, 0, 0);
    }
    __syncthreads();   // vmcnt(0)+lgkmcnt(0)+barrier: next tile ready, cur free for restage
    cur ^= 1;
  }

  // epilogue: C/D layout col=lane&15, row=(lane>>4)*4+j   [m89/m91]
  const int crow = (l >> 4) * 4, ccol = l & 15;
  unsigned short* outg = Out + (size_t)g * NROWS * HDIM;
#pragma unroll
  for (int mi = 0; mi < 4; ++mi) {
#pragma unroll
    for (int ni = 0; ni < 4; ++ni) {
      const int hcol = col0 + wcol + ni * 16 + ccol;
      const float bb = bias[g * HDIM + hcol];
#pragma unroll
      for (int j = 0; j < 4; ++j) {
        const int nrow = row0 + wrow + mi * 16 + crow + j;
        float v = acc[mi][ni][j] + bb;
        if (MODE == 1) {
          v += b2f(Madd[(size_t)g * NROWS * HDIM + (size_t)nrow * HDIM + hcol]);
          v = (g < 4) ? fast_sigmoid(v) : fast_tanh(v);
        } else {
          v = fast_tanh(v);
        }
        outg[(size_t)nrow * HDIM + hcol] = f2b(v);
      }
    }
  }
}

// ---------------- final elementwise combine (f32 q/c_prev, f32 out) ----------------

__device__ inline float exb(const uint4& v, int j) {
  unsigned int wd = ((const unsigned int*)&v)[j >> 1];
  return b2f((unsigned short)(wd >> ((j & 1) * 16)));
}

__global__ void combine(const unsigned short* __restrict__ gates,
                        const float* __restrict__ q,
                        const float* __restrict__ cp,
                        float* __restrict__ out) {
  const size_t NM = (size_t)NROWS * HDIM;
  size_t i8 = ((size_t)blockIdx.x * 256 + threadIdx.x) * 8;
  if (i8 >= NM) return;
  uint4 gi = *(const uint4*)(gates + 0 * NM + i8);
  uint4 gf = *(const uint4*)(gates + 1 * NM + i8);
  uint4 gl = *(const uint4*)(gates + 2 * NM + i8);
  uint4 go = *(const uint4*)(gates + 3 * NM + i8);
  uint4 gu = *(const uint4*)(gates + 4 * NM + i8);
  float4 q0 = *(const float4*)(q + i8);
  float4 q1 = *(const float4*)(q + i8 + 4);
  float4 p0 = *(const float4*)(cp + i8);
  float4 p1 = *(const float4*)(cp + i8 + 4);
  float qv[8] = {q0.x, q0.y, q0.z, q0.w, q1.x, q1.y, q1.z, q1.w};
  float pv[8] = {p0.x, p0.y, p0.z, p0.w, p1.x, p1.y, p1.z, p1.w};
  float hv[8], cv[8];
#pragma unroll
  for (int j = 0; j < 8; ++j) {
    float c = exb(gi, j) * exb(gu, j) + exb(gf, j) * qv[j] + exb(gl, j) * pv[j];
    hv[j] = exb(go, j) * fast_tanh(c);
    cv[j] = c;
  }
  *(float4*)(out + i8)      = make_float4(hv[0], hv[1], hv[2], hv[3]);
  *(float4*)(out + i8 + 4)  = make_float4(hv[4], hv[5], hv[6], hv[7]);
  *(float4*)(out + NM + i8)     = make_float4(cv[0], cv[1], cv[2], cv[3]);
  *(float4*)(out + NM + i8 + 4) = make_float4(cv[4], cv[5], cv[6], cv[7]);
}

// ---------------- launch ----------------

extern "C" void kernel_launch(void* const* d_in, const int* in_sizes, int n_in,
                              void* d_out, int out_size, void* d_ws, size_t ws_size,
                              hipStream_t stream) {
  const float* word  = (const float*)d_in[0];
  const float* tag   = (const float*)d_in[1];
  const float* rel   = (const float*)d_in[2];
  const float* kin   = (const float*)d_in[3];
  const float* qin   = (const float*)d_in[4];
  const float* hprev = (const float*)d_in[5];
  const float* cprev = (const float*)d_in[6];
  const float* Ww    = (const float*)d_in[7];
  const float* bw    = (const float*)d_in[8];
  const float* Wt    = (const float*)d_in[9];
  const float* bt    = (const float*)d_in[10];
  const float* Wr    = (const float*)d_in[11];
  const float* br    = (const float*)d_in[12];
  const float* Wh    = (const float*)d_in[13];
  const float* bh    = (const float*)d_in[14];
  const float* Wl    = (const float*)d_in[15];
  const float* bl    = (const float*)d_in[16];
  const float* Whp   = (const float*)d_in[17];
  const float* bhp   = (const float*)d_in[18];
  const float* Wk    = (const float*)d_in[19];
  const float* bk    = (const float*)d_in[20];

  char* ws = (char*)d_ws;
  unsigned short* xcat   = (unsigned short*)(ws);                 // 16,777,216 B
  unsigned short* Wcat   = (unsigned short*)(ws + 16777216);      //  2,621,440 B
  unsigned short* Whb    = (unsigned short*)(ws + 19398656);      //  2,621,440 B
  unsigned short* Wlb    = (unsigned short*)(ws + 22020096);      //  2,621,440 B
  unsigned short* Whpb   = (unsigned short*)(ws + 24641536);      //  2,621,440 B
  unsigned short* Wkb    = (unsigned short*)(ws + 27262976);      //  2,621,440 B
  unsigned short* hprevb = (unsigned short*)(ws + 29884416);      // 16,777,216 B
  unsigned short* kb16   = (unsigned short*)(ws + 46661632);      // 16,777,216 B
  float* bias0           = (float*)(ws + 63438848);               //     10,240 B
  float* bias1           = (float*)(ws + 63449088);
  float* bias2           = (float*)(ws + 63459328);
  float* biasD           = (float*)(ws + 63469568);
  unsigned short* bufA   = (unsigned short*)(ws + 63479808);      // 83,886,080 B
  unsigned short* bufB   = (unsigned short*)(ws + 147365888);     // 83,886,080 B
  // total: 231,251,968 B

  pack_x<<<32768, 256, 0, stream>>>(word, tag, rel, xcat);
  pack_w<<<5120, 256, 0, stream>>>(Ww, Wt, Wr, Wcat);
  cvt_bf16<<<1280, 256, 0, stream>>>(Wh, Whb, 1310720);
  cvt_bf16<<<1280, 256, 0, stream>>>(Wl, Wlb, 1310720);
  cvt_bf16<<<1280, 256, 0, stream>>>(Whp, Whpb, 1310720);
  cvt_bf16<<<1280, 256, 0, stream>>>(Wk, Wkb, 1310720);
  cvt_bf16<<<8192, 256, 0, stream>>>(hprev, hprevb, 8388608);
  cvt_bf16<<<8192, 256, 0, stream>>>(kin, kb16, 8388608);
  pack_bias<<<10, 256, 0, stream>>>(bw, bt, br, bh, bl, bhp, bk, bias0, bias1, bias2, biasD);

  dim3 grid((HDIM / 128) * GATES, NROWS / 128);
  // h0 = tanh(xcat W0^T + b0)
  gemm_nt<0><<<grid, 256, 0, stream>>>(xcat, nullptr, Wcat, nullptr, bias0, nullptr, bufA, 0, 8);
  // h1 = tanh(h0 Whid^T + bhid)
  gemm_nt<0><<<grid, 256, 0, stream>>>(bufA, nullptr, Whb, nullptr, bias1, nullptr, bufB, 1, 8);
  // m = tanh(h1 Wlast^T + blast)
  gemm_nt<0><<<grid, 256, 0, stream>>>(bufB, nullptr, Wlb, nullptr, bias2, nullptr, bufA, 1, 8);
  // gates = act(hprev Whp^T + k Wk^T + bhp + bk + m)
  gemm_nt<1><<<grid, 256, 0, stream>>>(hprevb, kb16, Whpb, Wkb, biasD, bufA, bufB, 0, 16);
  // c = i*u + f_down*q + f_left*c_prev ; h = o*tanh(c)
  combine<<<4096, 256, 0, stream>>>(bufB, qin, cprev, (float*)d_out);
}